// Round 3
// baseline (3031.703 us; speedup 1.0000x reference)
//
#include <hip/hip_runtime.h>
#include <math.h>

#define T 128
#define B 128
#define H 256
#define I 256
#define G4 1024  // 4*H

// ---------------- weight repack kernels (one-shot) ----------------
// WhP[k][j] = float4{ Whh[0*H+j][k], Whh[1*H+j][k], Whh[2*H+j][k], Whh[3*H+j][k] }
__global__ void pack_whh(const float* __restrict__ Whh, float4* __restrict__ WhP) {
    const int k = blockIdx.x;    // 0..H-1
    const int j = threadIdx.x;   // 0..H-1
    WhP[k * H + j] = make_float4(Whh[(0 * H + j) * H + k],
                                 Whh[(1 * H + j) * H + k],
                                 Whh[(2 * H + j) * H + k],
                                 Whh[(3 * H + j) * H + k]);
}

// WaP[k4][j] = float4{ Wa[j][4*k4 .. 4*k4+3] },  k4 in [0, 2H/4)
__global__ void pack_wa(const float* __restrict__ Wa, float4* __restrict__ WaP) {
    const int k4 = blockIdx.x;   // 0..127
    const int j  = threadIdx.x;  // 0..255
    WaP[k4 * H + j] = *(const float4*)&Wa[(size_t)j * (2 * H) + 4 * k4];
}

// ---------------- G = embs @ Wih^T + bih + bhh  (M=T*B, N=4H, K=I) ----------------
__global__ __launch_bounds__(256) void gemm_g(const float* __restrict__ A,   // [T*B][I]
                                              const float* __restrict__ W,   // [4H][I]
                                              const float* __restrict__ bih,
                                              const float* __restrict__ bhh,
                                              float* __restrict__ G) {       // [T*B][4H]
    __shared__ __align__(16) float As[64][68];  // [k][m], 68*4=272B row stride (16B mult)
    __shared__ __align__(16) float Ws[64][68];  // [k][n]
    const int m0 = blockIdx.x * 64;
    const int n0 = blockIdx.y * 64;
    const int tid = threadIdx.x;
    const int ty = tid >> 4, tx = tid & 15;
    const int rr = tid >> 4;     // row base for loads
    const int kr = tid & 15;     // float4 column for loads

    float acc[4][4] = {};
    for (int k0 = 0; k0 < I; k0 += 64) {
#pragma unroll
        for (int i = 0; i < 4; ++i) {
            const int r = rr + 16 * i;
            const float4 av = *(const float4*)&A[(size_t)(m0 + r) * I + k0 + kr * 4];
            const float4 wv = *(const float4*)&W[(size_t)(n0 + r) * I + k0 + kr * 4];
            As[kr * 4 + 0][r] = av.x; As[kr * 4 + 1][r] = av.y;
            As[kr * 4 + 2][r] = av.z; As[kr * 4 + 3][r] = av.w;
            Ws[kr * 4 + 0][r] = wv.x; Ws[kr * 4 + 1][r] = wv.y;
            Ws[kr * 4 + 2][r] = wv.z; Ws[kr * 4 + 3][r] = wv.w;
        }
        __syncthreads();
#pragma unroll 8
        for (int kk = 0; kk < 64; ++kk) {
            const float4 a4 = *(const float4*)&As[kk][ty * 4];
            const float4 w4 = *(const float4*)&Ws[kk][tx * 4];
            const float a[4] = {a4.x, a4.y, a4.z, a4.w};
            const float w[4] = {w4.x, w4.y, w4.z, w4.w};
#pragma unroll
            for (int i = 0; i < 4; ++i)
#pragma unroll
                for (int jj = 0; jj < 4; ++jj)
                    acc[i][jj] = fmaf(a[i], w[jj], acc[i][jj]);
        }
        __syncthreads();
    }
    const int n = n0 + tx * 4;
    const float4 bi = *(const float4*)&bih[n];
    const float4 bh = *(const float4*)&bhh[n];
    const float4 bb = make_float4(bi.x + bh.x, bi.y + bh.y, bi.z + bh.z, bi.w + bh.w);
#pragma unroll
    for (int i = 0; i < 4; ++i) {
        const int m = m0 + ty * 4 + i;
        float4 o = make_float4(acc[i][0] + bb.x, acc[i][1] + bb.y,
                               acc[i][2] + bb.z, acc[i][3] + bb.w);
        *(float4*)&G[(size_t)m * G4 + n] = o;
    }
}

// ---------------- recurrent attention-LSTM: one block per batch element ----------------
__global__ __launch_bounds__(256, 1) void alstm(
    const int* __restrict__ lens,
    const float* __restrict__ G,       // [T*B][4H] precomputed input gates
    const float4* __restrict__ WhP,    // [H][H] float4 (gate-interleaved Whh^T)
    const float4* __restrict__ WaP,    // [2H/4][H] float4 (Wa^T, k-packed)
    const float* __restrict__ ba,
    float* __restrict__ out)           // hs [T,B,H] | h_fin [B,H] | c_fin [B,H]
{
    __shared__ __align__(16) float hid_s[T * H];   // full per-batch output history, 128 KB
    __shared__ __align__(16) float h_s[H];         // current h
    __shared__ __align__(16) float hin_s[H];       // h_in (post-attention)
    __shared__ __align__(16) float ctx_s[H];
    __shared__ __align__(16) float sc_s[T];

    const int b = blockIdx.x;
    const int j = threadIdx.x;
    const int lane = j & 63;
    const int wave = j >> 6;
    const int len_b = lens[b];

    float c_reg = 0.f;
    h_s[j] = 0.f;
    const float ba_j = ba[j];
    float* hs_out = out;
    float* hfin = out + (size_t)T * B * H;
    float* cfin = hfin + (size_t)B * H;
    __syncthreads();

    for (int t = 0; t < T; ++t) {
        if (t > 0) {
            // ---- scores[t'] = h . hids[t'] (wave per t', strided) ----
            const float4 hc = *(const float4*)&h_s[lane * 4];
            for (int tp = wave; tp < t; tp += 4) {
                const float4 hv = *(const float4*)&hid_s[tp * H + lane * 4];
                float d = hv.x * hc.x + hv.y * hc.y + hv.z * hc.z + hv.w * hc.w;
#pragma unroll
                for (int off = 32; off > 0; off >>= 1) d += __shfl_xor(d, off);
                if (lane == 0) sc_s[tp] = d;
            }
            __syncthreads();
            // ---- softmax over t' (wave 0) ----
            if (wave == 0) {
                const float v0 = (lane < t) ? sc_s[lane] : -3.0e38f;
                const float v1 = (lane + 64 < t) ? sc_s[lane + 64] : -3.0e38f;
                float m = fmaxf(v0, v1);
#pragma unroll
                for (int off = 32; off > 0; off >>= 1) m = fmaxf(m, __shfl_xor(m, off));
                const float e0 = (lane < t) ? __expf(v0 - m) : 0.f;
                const float e1 = (lane + 64 < t) ? __expf(v1 - m) : 0.f;
                float s = e0 + e1;
#pragma unroll
                for (int off = 32; off > 0; off >>= 1) s += __shfl_xor(s, off);
                const float inv = 1.f / s;
                if (lane < t) sc_s[lane] = e0 * inv;
                if (lane + 64 < t) sc_s[lane + 64] = e1 * inv;
            }
            __syncthreads();
            // ---- ctx[j] = sum_t' w[t'] * hids[t'][j] ----
            float acc = 0.f;
            for (int tp = 0; tp < t; ++tp) acc = fmaf(sc_s[tp], hid_s[tp * H + j], acc);
            ctx_s[j] = acc;
            __syncthreads();
            // ---- h_att[j] = tanh(ba + Wa[j,:] . [h, ctx]) ----
            float a = ba_j;
#pragma unroll 4
            for (int k4 = 0; k4 < 64; ++k4) {
                const float4 w = WaP[k4 * H + j];
                a = fmaf(w.x, h_s[4 * k4 + 0], a);
                a = fmaf(w.y, h_s[4 * k4 + 1], a);
                a = fmaf(w.z, h_s[4 * k4 + 2], a);
                a = fmaf(w.w, h_s[4 * k4 + 3], a);
            }
#pragma unroll 4
            for (int k4 = 0; k4 < 64; ++k4) {
                const float4 w = WaP[(64 + k4) * H + j];
                a = fmaf(w.x, ctx_s[4 * k4 + 0], a);
                a = fmaf(w.y, ctx_s[4 * k4 + 1], a);
                a = fmaf(w.z, ctx_s[4 * k4 + 2], a);
                a = fmaf(w.w, ctx_s[4 * k4 + 3], a);
            }
            hin_s[j] = tanhf(a);
        } else {
            hin_s[j] = h_s[j];   // t=0: no attention, h_in = h0 (= 0)
        }
        __syncthreads();
        // ---- gates = G[t,b] + Whh^T-GEMV(h_in); cell update ----
        const float* Grow = G + (size_t)(t * B + b) * G4;
        float g0 = Grow[j], g1 = Grow[H + j], g2 = Grow[2 * H + j], g3 = Grow[3 * H + j];
#pragma unroll 4
        for (int k = 0; k < H; ++k) {
            const float hk = hin_s[k];
            const float4 w = WhP[k * H + j];
            g0 = fmaf(w.x, hk, g0);
            g1 = fmaf(w.y, hk, g1);
            g2 = fmaf(w.z, hk, g2);
            g3 = fmaf(w.w, hk, g3);
        }
        const float ig = 1.f / (1.f + expf(-g0));
        const float fg = 1.f / (1.f + expf(-g1));
        const float gg = tanhf(g2);
        const float og = 1.f / (1.f + expf(-g3));
        c_reg = fmaf(fg, c_reg, ig * gg);
        const float h_new = og * tanhf(c_reg);
        h_s[j] = h_new;               // safe: no h_s readers between here and loop-end sync
        hid_s[t * H + j] = h_new;
        hs_out[(size_t)(t * B + b) * H + j] = h_new;
        if (t == len_b - 1) {
            hfin[b * H + j] = h_new;
            cfin[b * H + j] = c_reg;
        }
        __syncthreads();
    }
}

extern "C" void kernel_launch(void* const* d_in, const int* in_sizes, int n_in,
                              void* d_out, int out_size, void* d_ws, size_t ws_size,
                              hipStream_t stream) {
    const float* embs = (const float*)d_in[0];
    const int*   lens = (const int*)d_in[1];
    const float* Wih  = (const float*)d_in[2];
    const float* Whh  = (const float*)d_in[3];
    const float* bih  = (const float*)d_in[4];
    const float* bhh  = (const float*)d_in[5];
    const float* Wa   = (const float*)d_in[6];
    const float* ba   = (const float*)d_in[7];
    float* out = (float*)d_out;

    // workspace layout (fp32): G [T*B][4H] | WhP [H*H] float4 | WaP [2H/4 * H] float4
    float* G   = (float*)d_ws;
    float* WhP = G + (size_t)T * B * G4;            // +64 MB
    float* WaP = WhP + (size_t)H * H * 4;           // +1 MB

    pack_whh<<<H, H, 0, stream>>>(Whh, (float4*)WhP);
    pack_wa<<<(2 * H) / 4, H, 0, stream>>>(Wa, (float4*)WaP);
    dim3 ggrid(T * B / 64, G4 / 64);
    gemm_g<<<ggrid, 256, 0, stream>>>(embs, Wih, bih, bhh, G);
    alstm<<<B, 256, 0, stream>>>(lens, G, (const float4*)WhP, (const float4*)WaP, ba, out);
}

// Round 5
// 2077.813 us; speedup vs baseline: 1.4591x; 1.4591x over previous
//
#include <hip/hip_runtime.h>
#include <math.h>

#define T 128
#define B 128
#define H 256
#define I 256
#define G4 1024  // 4*H

typedef unsigned short u16;
typedef unsigned int u32;

__device__ __forceinline__ float2 bf2_to_f2(u32 u) {
    union { u32 i; float f; } a, b;
    a.i = u << 16;
    b.i = u & 0xffff0000u;
    return make_float2(a.f, b.f);
}

__device__ __forceinline__ u16 bf16_rne(float f) {
    union { float f; u32 u; } x; x.f = f;
    u32 r = x.u + 0x7fffu + ((x.u >> 16) & 1u);
    return (u16)(r >> 16);
}

__device__ __forceinline__ float sigmoid_fast(float x) {
    return 1.0f / (1.0f + __expf(-x));
}
__device__ __forceinline__ float tanh_fast(float x) {
    x = fminf(fmaxf(x, -15.f), 15.f);
    const float e = __expf(2.0f * x);
    return (e - 1.0f) / (e + 1.0f);
}

// ---------------- weight repack (one-shot, bf16 k-major) ----------------
// WhB[k][o] = bf16(Whh[o][k]),  k<256 (H), o<1024 (4H gate-major)
__global__ void pack_whB(const float* __restrict__ Whh, u16* __restrict__ WhB) {
    const int k = blockIdx.x;       // 0..255
    const int o = threadIdx.x;      // 0..1023
    WhB[(size_t)k * G4 + o] = bf16_rne(Whh[(size_t)o * H + k]);
}
// WaB[k][j] = bf16(Wa[j][k]),  k<512 (2H), j<256 (H)
__global__ void pack_waB(const float* __restrict__ Wa, u16* __restrict__ WaB) {
    const int k = blockIdx.x;       // 0..511
    const int j = threadIdx.x;      // 0..255
    WaB[(size_t)k * H + j] = bf16_rne(Wa[(size_t)j * (2 * H) + k]);
}

// ---------------- G = embs @ Wih^T + bih + bhh  (M=T*B, N=4H, K=I) ----------------
__global__ __launch_bounds__(256) void gemm_g(const float* __restrict__ A,   // [T*B][I]
                                              const float* __restrict__ W,   // [4H][I]
                                              const float* __restrict__ bih,
                                              const float* __restrict__ bhh,
                                              float* __restrict__ G) {       // [T*B][4H]
    __shared__ __align__(16) float As[64][68];
    __shared__ __align__(16) float Ws[64][68];
    const int m0 = blockIdx.x * 64;
    const int n0 = blockIdx.y * 64;
    const int tid = threadIdx.x;
    const int ty = tid >> 4, tx = tid & 15;
    const int rr = tid >> 4;
    const int kr = tid & 15;

    float acc[4][4] = {};
    for (int k0 = 0; k0 < I; k0 += 64) {
#pragma unroll
        for (int i = 0; i < 4; ++i) {
            const int r = rr + 16 * i;
            const float4 av = *(const float4*)&A[(size_t)(m0 + r) * I + k0 + kr * 4];
            const float4 wv = *(const float4*)&W[(size_t)(n0 + r) * I + k0 + kr * 4];
            As[kr * 4 + 0][r] = av.x; As[kr * 4 + 1][r] = av.y;
            As[kr * 4 + 2][r] = av.z; As[kr * 4 + 3][r] = av.w;
            Ws[kr * 4 + 0][r] = wv.x; Ws[kr * 4 + 1][r] = wv.y;
            Ws[kr * 4 + 2][r] = wv.z; Ws[kr * 4 + 3][r] = wv.w;
        }
        __syncthreads();
#pragma unroll 8
        for (int kk = 0; kk < 64; ++kk) {
            const float4 a4 = *(const float4*)&As[kk][ty * 4];
            const float4 w4 = *(const float4*)&Ws[kk][tx * 4];
            const float a[4] = {a4.x, a4.y, a4.z, a4.w};
            const float w[4] = {w4.x, w4.y, w4.z, w4.w};
#pragma unroll
            for (int i = 0; i < 4; ++i)
#pragma unroll
                for (int jj = 0; jj < 4; ++jj)
                    acc[i][jj] = fmaf(a[i], w[jj], acc[i][jj]);
        }
        __syncthreads();
    }
    const int n = n0 + tx * 4;
    const float4 bi = *(const float4*)&bih[n];
    const float4 bh = *(const float4*)&bhh[n];
    const float4 bb = make_float4(bi.x + bh.x, bi.y + bh.y, bi.z + bh.z, bi.w + bh.w);
#pragma unroll
    for (int i = 0; i < 4; ++i) {
        const int m = m0 + ty * 4 + i;
        float4 o = make_float4(acc[i][0] + bb.x, acc[i][1] + bb.y,
                               acc[i][2] + bb.z, acc[i][3] + bb.w);
        *(float4*)&G[(size_t)m * G4 + n] = o;
    }
}

// ---------------- recurrent attention-LSTM: 1024 threads per batch element ----------------
__global__ __launch_bounds__(1024, 4) void alstm2(
    const int* __restrict__ lens,
    const float* __restrict__ G,       // [T*B][4H]
    const u16* __restrict__ WhB,       // [H][4H] bf16 k-major
    const u16* __restrict__ WaB,       // [2H][H] bf16 k-major
    const float* __restrict__ ba,
    float* __restrict__ out)           // hs [T,B,H] | h_fin [B,H] | c_fin [B,H]
{
    __shared__ __align__(16) float hid_s[T][H];   // 128 KB fp32 history
    __shared__ __align__(16) float red_s[4096];   // 16 KB reduce buffer (reused per phase)
    __shared__ __align__(16) float gate_s[G4];    // 4 KB
    __shared__ __align__(16) float h_s[H];
    __shared__ __align__(16) float hin_s[H];
    __shared__ __align__(16) float ctx_s[H];
    __shared__ __align__(16) float sc_s[T];

    const int b = blockIdx.x;
    const int tid = threadIdx.x;
    const int lane = tid & 63;
    const int wave = tid >> 6;
    const int len_b = lens[b];

    // Whh mapping: ko_h in [0,4) (64 k each), jo_h in [0,256) (outputs jo_h*4..+3)
    const int ko_h = tid >> 8;
    const int jo_h = tid & 255;
    // Wa mapping: ko_a in [0,16) (32 k each), jo_a in [0,64) (outputs jo_a*4..+3)
    const int ko_a = tid >> 6;
    const int jo_a = tid & 63;

    float c_reg = 0.f;                       // live in threads tid<256
    const float ba_j = (tid < H) ? ba[tid] : 0.f;
    if (tid < H) h_s[tid] = 0.f;
    float* hs_out = out;
    float* hfin = out + (size_t)T * B * H;
    float* cfin = hfin + (size_t)B * H;
    __syncthreads();

    for (int t = 0; t < T; ++t) {
        if (t > 0) {
            // ---- scores[t'] = h . hids[t'], one wave per t', 16 waves strided ----
            const float4 h4 = *(const float4*)&h_s[lane * 4];
            for (int tp = wave; tp < t; tp += 16) {
                const float4 hv = *(const float4*)&hid_s[tp][lane * 4];
                float d = hv.x * h4.x + hv.y * h4.y + hv.z * h4.z + hv.w * h4.w;
#pragma unroll
                for (int off = 32; off; off >>= 1) d += __shfl_xor(d, off);
                if (lane == 0) sc_s[tp] = d;
            }
            __syncthreads();
            // ---- softmax over t' (wave 0) ----
            if (wave == 0) {
                const float v0 = (lane < t) ? sc_s[lane] : -3.0e38f;
                const float v1 = (lane + 64 < t) ? sc_s[lane + 64] : -3.0e38f;
                float m = fmaxf(v0, v1);
#pragma unroll
                for (int off = 32; off; off >>= 1) m = fmaxf(m, __shfl_xor(m, off));
                const float e0 = (lane < t) ? __expf(v0 - m) : 0.f;
                const float e1 = (lane + 64 < t) ? __expf(v1 - m) : 0.f;
                float s = e0 + e1;
#pragma unroll
                for (int off = 32; off; off >>= 1) s += __shfl_xor(s, off);
                const float inv = 1.f / s;
                if (lane < t) sc_s[lane] = e0 * inv;
                if (lane + 64 < t) sc_s[lane + 64] = e1 * inv;
            }
            __syncthreads();
            // ---- ctx[j] = sum_t' w[t'] hids[t'][j], 4-way t-split ----
            {
                float cacc = 0.f;
                for (int tp = ko_h; tp < t; tp += 4)
                    cacc = fmaf(sc_s[tp], hid_s[tp][jo_h], cacc);
                red_s[ko_h * H + jo_h] = cacc;
            }
            __syncthreads();
            if (tid < H)
                ctx_s[tid] = red_s[tid] + red_s[H + tid] + red_s[2 * H + tid] + red_s[3 * H + tid];
            __syncthreads();
            // ---- Wa GEMV: h_att = tanh(Wa.[h|ctx] + ba), 16-way k-split ----
            {
                float a0 = 0.f, a1 = 0.f, a2 = 0.f, a3 = 0.f;
                const int kb = ko_a * 32;
#pragma unroll 8
                for (int kk = 0; kk < 32; ++kk) {
                    const int k = kb + kk;
                    const float vin = (k < H) ? h_s[k] : ctx_s[k - H];
                    const uint2 w = *(const uint2*)&WaB[(size_t)k * H + jo_a * 4];
                    const float2 w01 = bf2_to_f2(w.x), w23 = bf2_to_f2(w.y);
                    a0 = fmaf(w01.x, vin, a0); a1 = fmaf(w01.y, vin, a1);
                    a2 = fmaf(w23.x, vin, a2); a3 = fmaf(w23.y, vin, a3);
                }
                *(float4*)&red_s[ko_a * H + jo_a * 4] = make_float4(a0, a1, a2, a3);
            }
            __syncthreads();
            if (tid < H) {
                float a = ba_j;
#pragma unroll
                for (int r = 0; r < 16; ++r) a += red_s[r * H + tid];
                hin_s[tid] = tanh_fast(a);
            }
        } else {
            if (tid < H) hin_s[tid] = 0.f;   // h_in = h0 = 0
        }
        __syncthreads();
        // ---- Whh GEMV: 4-way k-split, outputs jo_h*4..+3 ----
        {
            float g0 = 0.f, g1 = 0.f, g2 = 0.f, g3 = 0.f;
            const int kb = ko_h * 64;
#pragma unroll 8
            for (int kk = 0; kk < 64; ++kk) {
                const int k = kb + kk;
                const float hk = hin_s[k];
                const uint2 w = *(const uint2*)&WhB[(size_t)k * G4 + jo_h * 4];
                const float2 w01 = bf2_to_f2(w.x), w23 = bf2_to_f2(w.y);
                g0 = fmaf(w01.x, hk, g0); g1 = fmaf(w01.y, hk, g1);
                g2 = fmaf(w23.x, hk, g2); g3 = fmaf(w23.y, hk, g3);
            }
            *(float4*)&red_s[ko_h * G4 + jo_h * 4] = make_float4(g0, g1, g2, g3);
        }
        __syncthreads();
        // ---- gate sum + input-GEMM row ----
        {
            const float* Grow = G + (size_t)(t * B + b) * G4;
            gate_s[tid] = Grow[tid] + red_s[tid] + red_s[G4 + tid]
                        + red_s[2 * G4 + tid] + red_s[3 * G4 + tid];
        }
        __syncthreads();
        // ---- cell update (threads 0..255) ----
        if (tid < H) {
            const float ig = sigmoid_fast(gate_s[tid]);
            const float fg = sigmoid_fast(gate_s[H + tid]);
            const float gg = tanh_fast(gate_s[2 * H + tid]);
            const float og = sigmoid_fast(gate_s[3 * H + tid]);
            c_reg = fmaf(fg, c_reg, ig * gg);
            const float h_new = og * tanh_fast(c_reg);
            h_s[tid] = h_new;
            hid_s[t][tid] = h_new;
            hs_out[(size_t)(t * B + b) * H + tid] = h_new;
            if (t == len_b - 1) {
                hfin[b * H + tid] = h_new;
                cfin[b * H + tid] = c_reg;
            }
        }
        __syncthreads();
    }
}

extern "C" void kernel_launch(void* const* d_in, const int* in_sizes, int n_in,
                              void* d_out, int out_size, void* d_ws, size_t ws_size,
                              hipStream_t stream) {
    const float* embs = (const float*)d_in[0];
    const int*   lens = (const int*)d_in[1];
    const float* Wih  = (const float*)d_in[2];
    const float* Whh  = (const float*)d_in[3];
    const float* bih  = (const float*)d_in[4];
    const float* bhh  = (const float*)d_in[5];
    const float* Wa   = (const float*)d_in[6];
    const float* ba   = (const float*)d_in[7];
    float* out = (float*)d_out;

    // ws layout: G fp32 [T*B][4H] (64 MB) | WhB bf16 [H][4H] (512 KB) | WaB bf16 [2H][H] (256 KB)
    float* G  = (float*)d_ws;
    u16* WhB  = (u16*)(G + (size_t)T * B * G4);
    u16* WaB  = WhB + (size_t)H * G4;

    pack_whB<<<H, G4, 0, stream>>>(Whh, WhB);
    pack_waB<<<2 * H, H, 0, stream>>>(Wa, WaB);
    dim3 ggrid(T * B / 64, G4 / 64);
    gemm_g<<<ggrid, 256, 0, stream>>>(embs, Wih, bih, bhh, G);
    alstm2<<<B, 1024, 0, stream>>>(lens, G, WhB, WaB, ba, out);
}

// Round 6
// 2043.053 us; speedup vs baseline: 1.4839x; 1.0170x over previous
//
#include <hip/hip_runtime.h>
#include <math.h>

#define T 128
#define B 128
#define H 256
#define I 256
#define G4 1024  // 4*H
#define NB 2     // batch elements per block

typedef unsigned short u16;
typedef unsigned int u32;

__device__ __forceinline__ float2 bf2_to_f2(u32 u) {
    union { u32 i; float f; } a, b;
    a.i = u << 16;
    b.i = u & 0xffff0000u;
    return make_float2(a.f, b.f);
}
__device__ __forceinline__ float bf1_to_f(u16 u) {
    union { u32 i; float f; } a; a.i = ((u32)u) << 16; return a.f;
}
__device__ __forceinline__ u16 bf16_rne(float f) {
    union { float f; u32 u; } x; x.f = f;
    u32 r = x.u + 0x7fffu + ((x.u >> 16) & 1u);
    return (u16)(r >> 16);
}
__device__ __forceinline__ float sigmoid_fast(float x) {
    return 1.0f / (1.0f + __expf(-x));
}
__device__ __forceinline__ float tanh_fast(float x) {
    x = fminf(fmaxf(x, -15.f), 15.f);
    const float e = __expf(2.0f * x);
    return (e - 1.0f) / (e + 1.0f);
}

// ---------------- weight repack (one-shot, bf16 k-major) ----------------
__global__ void pack_whB(const float* __restrict__ Whh, u16* __restrict__ WhB) {
    const int k = blockIdx.x;       // 0..255
    const int o = threadIdx.x;      // 0..1023
    WhB[(size_t)k * G4 + o] = bf16_rne(Whh[(size_t)o * H + k]);
}
__global__ void pack_waB(const float* __restrict__ Wa, u16* __restrict__ WaB) {
    const int k = blockIdx.x;       // 0..511
    const int j = threadIdx.x;      // 0..255
    WaB[(size_t)k * H + j] = bf16_rne(Wa[(size_t)j * (2 * H) + k]);
}

// ---------------- G = embs @ Wih^T + bih + bhh ----------------
__global__ __launch_bounds__(256) void gemm_g(const float* __restrict__ A,
                                              const float* __restrict__ W,
                                              const float* __restrict__ bih,
                                              const float* __restrict__ bhh,
                                              float* __restrict__ G) {
    __shared__ __align__(16) float As[64][68];
    __shared__ __align__(16) float Ws[64][68];
    const int m0 = blockIdx.x * 64;
    const int n0 = blockIdx.y * 64;
    const int tid = threadIdx.x;
    const int ty = tid >> 4, tx = tid & 15;
    const int rr = tid >> 4;
    const int kr = tid & 15;

    float acc[4][4] = {};
    for (int k0 = 0; k0 < I; k0 += 64) {
#pragma unroll
        for (int i = 0; i < 4; ++i) {
            const int r = rr + 16 * i;
            const float4 av = *(const float4*)&A[(size_t)(m0 + r) * I + k0 + kr * 4];
            const float4 wv = *(const float4*)&W[(size_t)(n0 + r) * I + k0 + kr * 4];
            As[kr * 4 + 0][r] = av.x; As[kr * 4 + 1][r] = av.y;
            As[kr * 4 + 2][r] = av.z; As[kr * 4 + 3][r] = av.w;
            Ws[kr * 4 + 0][r] = wv.x; Ws[kr * 4 + 1][r] = wv.y;
            Ws[kr * 4 + 2][r] = wv.z; Ws[kr * 4 + 3][r] = wv.w;
        }
        __syncthreads();
#pragma unroll 8
        for (int kk = 0; kk < 64; ++kk) {
            const float4 a4 = *(const float4*)&As[kk][ty * 4];
            const float4 w4 = *(const float4*)&Ws[kk][tx * 4];
            const float a[4] = {a4.x, a4.y, a4.z, a4.w};
            const float w[4] = {w4.x, w4.y, w4.z, w4.w};
#pragma unroll
            for (int i = 0; i < 4; ++i)
#pragma unroll
                for (int jj = 0; jj < 4; ++jj)
                    acc[i][jj] = fmaf(a[i], w[jj], acc[i][jj]);
        }
        __syncthreads();
    }
    const int n = n0 + tx * 4;
    const float4 bi = *(const float4*)&bih[n];
    const float4 bh = *(const float4*)&bhh[n];
    const float4 bb = make_float4(bi.x + bh.x, bi.y + bh.y, bi.z + bh.z, bi.w + bh.w);
#pragma unroll
    for (int i = 0; i < 4; ++i) {
        const int m = m0 + ty * 4 + i;
        float4 o = make_float4(acc[i][0] + bb.x, acc[i][1] + bb.y,
                               acc[i][2] + bb.z, acc[i][3] + bb.w);
        *(float4*)&G[(size_t)m * G4 + n] = o;
    }
}

// ---------------- recurrent attention-LSTM: 2 batch elements per block ----------------
// LDS budget (bytes): hid 131072 + red 16384 + gate 8192 + h 2048 + hin 2048
//                     + ctx 2048 + sc 1024 = 162816 <= 163840 (1 block/CU, 16 waves)
__global__ __launch_bounds__(1024, 4) void alstm3(
    const int* __restrict__ lens,
    const float* __restrict__ G,       // [T*B][4H]
    const u16* __restrict__ WhB,       // [H][4H] bf16 k-major
    const u16* __restrict__ WaB,       // [2H][H] bf16 k-major
    const float* __restrict__ ba,
    float* __restrict__ out)           // hs | h_fin | c_fin
{
    __shared__ __align__(16) u16   hid_s[NB][T][H];   // bf16 history
    __shared__ __align__(16) float red_s[4096];       // 16 KB phase-reuse reduce buffer
    __shared__ __align__(16) float gate_s[NB][G4];
    __shared__ __align__(16) float h_s[NB][H];
    __shared__ __align__(16) float hin_s[NB][H];
    __shared__ __align__(16) float ctx_s[NB][H];
    __shared__ __align__(16) float sc_s[NB][T];

    const int b0 = blockIdx.x * NB;
    const int tid = threadIdx.x;
    const int lane = tid & 63;
    const int wave = tid >> 6;        // 0..15
    // scores map: waves 0-7 -> batch 0, 8-15 -> batch 1
    const int sb = wave >> 3;
    const int stp0 = wave & 7;
    // ctx map: cb batch, ck 2-way t-split, cj feature
    const int cb = tid >> 9;
    const int ck = (tid >> 8) & 1;
    const int cj = tid & 255;
    // Wa map: ako 64-k chunk (0..7), aj output j-pair
    const int ako = tid >> 7;
    const int aj = (tid & 127) * 2;
    // Whh map: hko 128-k chunk (0..1), ho output o-pair
    const int hko = tid >> 9;
    const int ho = (tid & 511) * 2;
    // cell/reduce map (threads 0..511): eb batch, ej feature
    const int eb = tid >> 8;
    const int ej = tid & 255;

    const int len0 = lens[b0], len1 = lens[b0 + 1];
    float c_reg = 0.f;
    if (tid < NB * H) h_s[eb][ej] = 0.f;
    float* hfin = out + (size_t)T * B * H;
    float* cfin = hfin + (size_t)B * H;
    __syncthreads();

    for (int t = 0; t < T; ++t) {
        // ---- prefetch this step's G rows (consumed at gate_s stash) ----
        const float gA = G[((size_t)t * B + b0) * G4 + tid];
        const float gB = G[((size_t)t * B + b0 + 1) * G4 + tid];

        if (t > 0) {
            // ---- scores: 8 waves per batch, t' strided ----
            const float4 h4 = *(const float4*)&h_s[sb][lane * 4];
            for (int tp = stp0; tp < t; tp += 8) {
                const uint2 hv = *(const uint2*)&hid_s[sb][tp][lane * 4];
                const float2 ha = bf2_to_f2(hv.x);
                const float2 hb = bf2_to_f2(hv.y);
                float d = ha.x * h4.x + ha.y * h4.y + hb.x * h4.z + hb.y * h4.w;
#pragma unroll
                for (int off = 32; off; off >>= 1) d += __shfl_xor(d, off);
                if (lane == 0) sc_s[sb][tp] = d;
            }
            __syncthreads();
            // ---- softmax: wave 0 -> batch 0, wave 8 -> batch 1 (parallel) ----
            if (stp0 == 0) {
                const float v0 = (lane < t) ? sc_s[sb][lane] : -3.0e38f;
                const float v1 = (lane + 64 < t) ? sc_s[sb][lane + 64] : -3.0e38f;
                float m = fmaxf(v0, v1);
#pragma unroll
                for (int off = 32; off; off >>= 1) m = fmaxf(m, __shfl_xor(m, off));
                const float e0 = (lane < t) ? __expf(v0 - m) : 0.f;
                const float e1 = (lane + 64 < t) ? __expf(v1 - m) : 0.f;
                float s = e0 + e1;
#pragma unroll
                for (int off = 32; off; off >>= 1) s += __shfl_xor(s, off);
                const float inv = 1.f / s;
                if (lane < t) sc_s[sb][lane] = e0 * inv;
                if (lane + 64 < t) sc_s[sb][lane + 64] = e1 * inv;
            }
            __syncthreads();
            // ---- ctx partial (2-way t-split per batch) + G stash ----
            {
                float cacc = 0.f;
#pragma unroll 4
                for (int tp = ck; tp < t; tp += 2)
                    cacc = fmaf(sc_s[cb][tp], bf1_to_f(hid_s[cb][tp][cj]), cacc);
                red_s[cb * 512 + ck * 256 + cj] = cacc;
                gate_s[0][tid] = gA;
                gate_s[1][tid] = gB;
            }
            __syncthreads();
            if (tid < 512)
                ctx_s[eb][ej] = red_s[eb * 512 + ej] + red_s[eb * 512 + 256 + ej];
            __syncthreads();
            // ---- Wa GEMV: shared weight stream, both batches ----
            {
                const float* base0 = (ako < 4) ? &h_s[0][ako * 64] : &ctx_s[0][ako * 64 - 256];
                const float* base1 = (ako < 4) ? &h_s[1][ako * 64] : &ctx_s[1][ako * 64 - 256];
                const u16* wp = &WaB[(size_t)(ako * 64) * H + aj];
                float a00 = 0.f, a01 = 0.f, a10 = 0.f, a11 = 0.f;
#pragma unroll 8
                for (int kk = 0; kk < 64; ++kk) {
                    const u32 w = *(const u32*)(wp + (size_t)kk * H);
                    const float2 wv = bf2_to_f2(w);
                    const float v0 = base0[kk];
                    const float v1 = base1[kk];
                    a00 = fmaf(wv.x, v0, a00); a01 = fmaf(wv.y, v0, a01);
                    a10 = fmaf(wv.x, v1, a10); a11 = fmaf(wv.y, v1, a11);
                }
                *(float2*)&red_s[ako * 512 + aj] = make_float2(a00, a01);
                *(float2*)&red_s[ako * 512 + 256 + aj] = make_float2(a10, a11);
            }
            __syncthreads();
            if (tid < 512) {
                float a = ba[ej];
#pragma unroll
                for (int r = 0; r < 8; ++r) a += red_s[r * 512 + eb * 256 + ej];
                hin_s[eb][ej] = tanh_fast(a);
            }
            __syncthreads();
        } else {
            gate_s[0][tid] = gA;
            gate_s[1][tid] = gB;
            if (tid < 512) hin_s[eb][ej] = 0.f;
            __syncthreads();
        }
        // ---- Whh GEMV: shared weight stream, both batches ----
        {
            const u16* wp = &WhB[(size_t)(hko * 128) * G4 + ho];
            float a00 = 0.f, a01 = 0.f, a10 = 0.f, a11 = 0.f;
#pragma unroll 8
            for (int kk = 0; kk < 128; ++kk) {
                const int k = hko * 128 + kk;
                const u32 w = *(const u32*)(wp + (size_t)kk * G4);
                const float2 wv = bf2_to_f2(w);
                const float h0 = hin_s[0][k];
                const float h1 = hin_s[1][k];
                a00 = fmaf(wv.x, h0, a00); a01 = fmaf(wv.y, h0, a01);
                a10 = fmaf(wv.x, h1, a10); a11 = fmaf(wv.y, h1, a11);
            }
            *(float2*)&red_s[hko * 2048 + ho] = make_float2(a00, a01);
            *(float2*)&red_s[hko * 2048 + 1024 + ho] = make_float2(a10, a11);
        }
        __syncthreads();
        // ---- gate sum + cell update (threads 0..511) ----
        if (tid < 512) {
            const int bg = b0 + eb;
            const float gi = gate_s[eb][ej] + red_s[eb * 1024 + ej] + red_s[2048 + eb * 1024 + ej];
            const float gf = gate_s[eb][H + ej] + red_s[eb * 1024 + H + ej] + red_s[2048 + eb * 1024 + H + ej];
            const float gg = gate_s[eb][2 * H + ej] + red_s[eb * 1024 + 2 * H + ej] + red_s[2048 + eb * 1024 + 2 * H + ej];
            const float go = gate_s[eb][3 * H + ej] + red_s[eb * 1024 + 3 * H + ej] + red_s[2048 + eb * 1024 + 3 * H + ej];
            const float ig = sigmoid_fast(gi);
            const float fg = sigmoid_fast(gf);
            const float gv = tanh_fast(gg);
            const float og = sigmoid_fast(go);
            c_reg = fmaf(fg, c_reg, ig * gv);
            const float h_new = og * tanh_fast(c_reg);
            h_s[eb][ej] = h_new;
            hid_s[eb][t][ej] = bf16_rne(h_new);
            out[((size_t)t * B + bg) * H + ej] = h_new;
            const int lb = eb ? len1 : len0;
            if (t == lb - 1) {
                hfin[(size_t)bg * H + ej] = h_new;
                cfin[(size_t)bg * H + ej] = c_reg;
            }
        }
        __syncthreads();
    }
}

extern "C" void kernel_launch(void* const* d_in, const int* in_sizes, int n_in,
                              void* d_out, int out_size, void* d_ws, size_t ws_size,
                              hipStream_t stream) {
    const float* embs = (const float*)d_in[0];
    const int*   lens = (const int*)d_in[1];
    const float* Wih  = (const float*)d_in[2];
    const float* Whh  = (const float*)d_in[3];
    const float* bih  = (const float*)d_in[4];
    const float* bhh  = (const float*)d_in[5];
    const float* Wa   = (const float*)d_in[6];
    const float* ba   = (const float*)d_in[7];
    float* out = (float*)d_out;

    // ws layout: G fp32 [T*B][4H] (64 MB) | WhB bf16 (512 KB) | WaB bf16 (256 KB)
    float* G  = (float*)d_ws;
    u16* WhB  = (u16*)(G + (size_t)T * B * G4);
    u16* WaB  = WhB + (size_t)H * G4;

    pack_whB<<<H, G4, 0, stream>>>(Whh, WhB);
    pack_waB<<<2 * H, H, 0, stream>>>(Wa, WaB);
    dim3 ggrid(T * B / 64, G4 / 64);
    gemm_g<<<ggrid, 256, 0, stream>>>(embs, Wih, bih, bhh, G);
    alstm3<<<B / NB, 1024, 0, stream>>>(lens, G, WhB, WaB, ba, out);
}

// Round 8
// 1885.610 us; speedup vs baseline: 1.6078x; 1.0835x over previous
//
#include <hip/hip_runtime.h>
#include <math.h>

#define T 128
#define B 128
#define H 256
#define I 256
#define G4 1024  // 4*H
#define NB 2     // batch elements per block

typedef unsigned short u16;
typedef unsigned int u32;
typedef _Float16 half_t;
typedef _Float16 half2_t __attribute__((ext_vector_type(2)));

#if defined(__has_builtin)
#if __has_builtin(__builtin_amdgcn_fdot2)
#define HAS_FDOT2 1
#endif
#endif

__device__ __forceinline__ float fdot2(half2_t a, half2_t b, float c) {
#ifdef HAS_FDOT2
    return __builtin_amdgcn_fdot2(a, b, c, false);
#else
    return fmaf((float)a.x, (float)b.x, fmaf((float)a.y, (float)b.y, c));
#endif
}
__device__ __forceinline__ half2_t h2cast(u32 u) { return __builtin_bit_cast(half2_t, u); }

__device__ __forceinline__ float sigmoid_fast(float x) {
    return 1.0f / (1.0f + __expf(-x));
}
__device__ __forceinline__ float tanh_fast(float x) {
    x = fminf(fmaxf(x, -15.f), 15.f);
    const float e = __expf(2.0f * x);
    return (e - 1.0f) / (e + 1.0f);
}

// ---------------- weight repack (one-shot, fp16 k-pair-major) ----------------
// WhH[k2][o] = half2{Whh[o][2k2], Whh[o][2k2+1]},  k2<128, o<1024
__global__ void pack_whH(const float* __restrict__ Whh, half2_t* __restrict__ WhH) {
    const int k2 = blockIdx.x;      // 0..127
    const int o  = threadIdx.x;     // 0..1023
    half2_t v;
    v.x = (half_t)Whh[(size_t)o * H + 2 * k2];
    v.y = (half_t)Whh[(size_t)o * H + 2 * k2 + 1];
    WhH[(size_t)k2 * G4 + o] = v;
}
// WaH[k2][j] = half2{Wa[j][2k2], Wa[j][2k2+1]},  k2<256, j<256
__global__ void pack_waH(const float* __restrict__ Wa, half2_t* __restrict__ WaH) {
    const int k2 = blockIdx.x;      // 0..255
    const int j  = threadIdx.x;     // 0..255
    half2_t v;
    v.x = (half_t)Wa[(size_t)j * (2 * H) + 2 * k2];
    v.y = (half_t)Wa[(size_t)j * (2 * H) + 2 * k2 + 1];
    WaH[(size_t)k2 * H + j] = v;
}

// ---------------- G = embs @ Wih^T + bih + bhh ----------------
__global__ __launch_bounds__(256) void gemm_g(const float* __restrict__ A,
                                              const float* __restrict__ W,
                                              const float* __restrict__ bih,
                                              const float* __restrict__ bhh,
                                              float* __restrict__ G) {
    __shared__ __align__(16) float As[64][68];
    __shared__ __align__(16) float Ws[64][68];
    const int m0 = blockIdx.x * 64;
    const int n0 = blockIdx.y * 64;
    const int tid = threadIdx.x;
    const int ty = tid >> 4, tx = tid & 15;
    const int rr = tid >> 4;
    const int kr = tid & 15;

    float acc[4][4] = {};
    for (int k0 = 0; k0 < I; k0 += 64) {
#pragma unroll
        for (int i = 0; i < 4; ++i) {
            const int r = rr + 16 * i;
            const float4 av = *(const float4*)&A[(size_t)(m0 + r) * I + k0 + kr * 4];
            const float4 wv = *(const float4*)&W[(size_t)(n0 + r) * I + k0 + kr * 4];
            As[kr * 4 + 0][r] = av.x; As[kr * 4 + 1][r] = av.y;
            As[kr * 4 + 2][r] = av.z; As[kr * 4 + 3][r] = av.w;
            Ws[kr * 4 + 0][r] = wv.x; Ws[kr * 4 + 1][r] = wv.y;
            Ws[kr * 4 + 2][r] = wv.z; Ws[kr * 4 + 3][r] = wv.w;
        }
        __syncthreads();
#pragma unroll 8
        for (int kk = 0; kk < 64; ++kk) {
            const float4 a4 = *(const float4*)&As[kk][ty * 4];
            const float4 w4 = *(const float4*)&Ws[kk][tx * 4];
            const float a[4] = {a4.x, a4.y, a4.z, a4.w};
            const float w[4] = {w4.x, w4.y, w4.z, w4.w};
#pragma unroll
            for (int i = 0; i < 4; ++i)
#pragma unroll
                for (int jj = 0; jj < 4; ++jj)
                    acc[i][jj] = fmaf(a[i], w[jj], acc[i][jj]);
        }
        __syncthreads();
    }
    const int n = n0 + tx * 4;
    const float4 bi = *(const float4*)&bih[n];
    const float4 bh = *(const float4*)&bhh[n];
    const float4 bb = make_float4(bi.x + bh.x, bi.y + bh.y, bi.z + bh.z, bi.w + bh.w);
#pragma unroll
    for (int i = 0; i < 4; ++i) {
        const int m = m0 + ty * 4 + i;
        float4 o = make_float4(acc[i][0] + bb.x, acc[i][1] + bb.y,
                               acc[i][2] + bb.z, acc[i][3] + bb.w);
        *(float4*)&G[(size_t)m * G4 + n] = o;
    }
}

// ---------------- recurrent attention-LSTM: 2 batch elements per block, fp16 dot2 ----------------
// LDS: hid 131072 + sc 1024 + hH 1024 + hcI 2048 + hinI 1024 + red 8192 + gate 8192
//      = 152576 B <= 163840 (1 block/CU, 16 waves)
__global__ __launch_bounds__(1024, 4) void alstm4(
    const int* __restrict__ lens,
    const float* __restrict__ G,       // [T*B][4H]
    const half2_t* __restrict__ WhH,   // [128][1024] k2-major
    const half2_t* __restrict__ WaH,   // [256][256]  k2-major
    const float* __restrict__ ba,
    float* __restrict__ out)           // hs | h_fin | c_fin
{
    __shared__ __align__(16) half_t hid_s[NB][T][H];   // fp16 history, 128 KB
    __shared__ __align__(16) float  sc_s[NB][T];
    __shared__ __align__(16) half_t hH_s[NB][H];       // h (for scores)
    __shared__ __align__(16) half_t hcI_s[4 * 256];    // [h|ctx], batch-interleaved k-pairs
    __shared__ __align__(16) half_t hinI_s[4 * 128];   // hin, batch-interleaved k-pairs
    __shared__ __align__(16) float  red_s[2048];       // phase-reuse reduce buffer
    __shared__ __align__(16) float  gate_s[NB][G4];    // prefetched G rows

    const int b0 = blockIdx.x * NB;
    const int tid = threadIdx.x;
    const int lane = tid & 63;
    const int wave = tid >> 6;        // 0..15
    // scores: waves 0-7 -> batch 0, 8-15 -> batch 1
    const int sb = wave >> 3;
    const int stp0 = wave & 7;
    // ctx: cb batch, ck 2-way t-split, cj feature
    const int cb = tid >> 9;
    const int ck = (tid >> 8) & 1;
    const int cj = tid & 255;
    // Wa: ako 64-k2 chunk (0..3), aj output j
    const int ako = tid >> 8;
    const int aj = tid & 255;
    // cell/reduce (threads 0..511): eb batch, ej feature
    const int eb = tid >> 8;
    const int ej = tid & 255;

    const int len0 = lens[b0], len1 = lens[b0 + 1];
    float c_reg = 0.f;
    float* hfin = out + (size_t)T * B * H;
    float* cfin = hfin + (size_t)B * H;
    if (tid < 512) hH_s[eb][ej] = (half_t)0.f;
    __syncthreads();

    for (int t = 0; t < T; ++t) {
        // prefetch this step's G rows (stashed into gate_s mid-phase)
        const float gA = G[((size_t)t * B + b0) * G4 + tid];
        const float gB = G[((size_t)t * B + b0 + 1) * G4 + tid];

        if (t > 0) {
            // ---- scores: 8 waves per batch, t' strided ----
            const half2_t h2a = h2cast(*(const u32*)&hH_s[sb][lane * 4]);
            const half2_t h2b = h2cast(*(const u32*)&hH_s[sb][lane * 4 + 2]);
            for (int tp = stp0; tp < t; tp += 8) {
                const uint2 hv = *(const uint2*)&hid_s[sb][tp][lane * 4];
                float d = fdot2(h2cast(hv.x), h2a, fdot2(h2cast(hv.y), h2b, 0.f));
#pragma unroll
                for (int off = 32; off; off >>= 1) d += __shfl_xor(d, off);
                if (lane == 0) sc_s[sb][tp] = d;
            }
            __syncthreads();
            // ---- softmax: wave 0 -> batch 0, wave 8 -> batch 1 ----
            if (stp0 == 0) {
                const float v0 = (lane < t) ? sc_s[sb][lane] : -3.0e38f;
                const float v1 = (lane + 64 < t) ? sc_s[sb][lane + 64] : -3.0e38f;
                float m = fmaxf(v0, v1);
#pragma unroll
                for (int off = 32; off; off >>= 1) m = fmaxf(m, __shfl_xor(m, off));
                const float e0 = (lane < t) ? __expf(v0 - m) : 0.f;
                const float e1 = (lane + 64 < t) ? __expf(v1 - m) : 0.f;
                float s = e0 + e1;
#pragma unroll
                for (int off = 32; off; off >>= 1) s += __shfl_xor(s, off);
                const float inv = 1.f / s;
                if (lane < t) sc_s[sb][lane] = e0 * inv;
                if (lane + 64 < t) sc_s[sb][lane + 64] = e1 * inv;
            }
            __syncthreads();
            // ---- ctx partials (2-way t-split) + G stash ----
            {
                float cacc = 0.f;
                for (int tp = ck; tp < t; tp += 2)
                    cacc = fmaf(sc_s[cb][tp], (float)hid_s[cb][tp][cj], cacc);
                red_s[cb * 512 + ck * 256 + cj] = cacc;
                gate_s[0][tid] = gA;
                gate_s[1][tid] = gB;
            }
            __syncthreads();
            if (tid < 512) {
                const float ctxv = red_s[eb * 512 + ej] + red_s[eb * 512 + 256 + ej];
                hcI_s[512 + 4 * (ej >> 1) + 2 * eb + (ej & 1)] = (half_t)ctxv;
            }
            __syncthreads();
            // ---- Wa GEMV (fdot2, shared weight stream) ----
            {
                const half2_t* wp = &WaH[(size_t)(ako * 64) * H + aj];
                float a0 = 0.f, a1 = 0.f;
#pragma unroll 8
                for (int kk = 0; kk < 64; ++kk) {
                    const int k2 = ako * 64 + kk;
                    const uint2 hh = *(const uint2*)&hcI_s[4 * k2];
                    const half2_t w = wp[(size_t)kk * H];
                    a0 = fdot2(w, h2cast(hh.x), a0);
                    a1 = fdot2(w, h2cast(hh.y), a1);
                }
                red_s[ako * 512 + aj] = a0;
                red_s[ako * 512 + 256 + aj] = a1;
            }
            __syncthreads();
            if (tid < 512) {
                float a = ba[ej];
#pragma unroll
                for (int r = 0; r < 4; ++r) a += red_s[r * 512 + eb * 256 + ej];
                hinI_s[4 * (ej >> 1) + 2 * eb + (ej & 1)] = (half_t)tanh_fast(a);
            }
            __syncthreads();
        } else {
            gate_s[0][tid] = gA;
            gate_s[1][tid] = gB;
            if (tid < 512) hinI_s[tid] = (half_t)0.f;
            __syncthreads();
        }
        // ---- Whh GEMV: one output per thread, both batches, fdot2 ----
        {
            const half2_t* wp = &WhH[tid];
            float g0 = 0.f, g1 = 0.f;
#pragma unroll 8
            for (int k2 = 0; k2 < 128; ++k2) {
                const uint2 hh = *(const uint2*)&hinI_s[4 * k2];
                const half2_t w = wp[(size_t)k2 * G4];
                g0 = fdot2(w, h2cast(hh.x), g0);
                g1 = fdot2(w, h2cast(hh.y), g1);
            }
            red_s[tid] = g0;
            red_s[1024 + tid] = g1;
        }
        __syncthreads();
        // ---- gate sum + cell update (threads 0..511) ----
        if (tid < 512) {
            const int bg = b0 + eb;
            const float gi = gate_s[eb][ej]           + red_s[eb * 1024 + ej];
            const float gf = gate_s[eb][H + ej]       + red_s[eb * 1024 + H + ej];
            const float gg = gate_s[eb][2 * H + ej]   + red_s[eb * 1024 + 2 * H + ej];
            const float go = gate_s[eb][3 * H + ej]   + red_s[eb * 1024 + 3 * H + ej];
            const float ig = sigmoid_fast(gi);
            const float fg = sigmoid_fast(gf);
            const float gv = tanh_fast(gg);
            const float og = sigmoid_fast(go);
            c_reg = fmaf(fg, c_reg, ig * gv);
            const float h_new = og * tanh_fast(c_reg);
            const half_t hh = (half_t)h_new;
            hH_s[eb][ej] = hh;
            hid_s[eb][t][ej] = hh;
            hcI_s[4 * (ej >> 1) + 2 * eb + (ej & 1)] = hh;
            out[((size_t)t * B + bg) * H + ej] = h_new;
            const int lb = eb ? len1 : len0;
            if (t == lb - 1) {
                hfin[(size_t)bg * H + ej] = h_new;
                cfin[(size_t)bg * H + ej] = c_reg;
            }
        }
        __syncthreads();
    }
}

extern "C" void kernel_launch(void* const* d_in, const int* in_sizes, int n_in,
                              void* d_out, int out_size, void* d_ws, size_t ws_size,
                              hipStream_t stream) {
    const float* embs = (const float*)d_in[0];
    const int*   lens = (const int*)d_in[1];
    const float* Wih  = (const float*)d_in[2];
    const float* Whh  = (const float*)d_in[3];
    const float* bih  = (const float*)d_in[4];
    const float* bhh  = (const float*)d_in[5];
    const float* Wa   = (const float*)d_in[6];
    const float* ba   = (const float*)d_in[7];
    float* out = (float*)d_out;

    // ws layout: G fp32 [T*B][4H] (64 MB) | WhH half2[128*1024] (512 KB) | WaH half2[256*256] (256 KB)
    float* G      = (float*)d_ws;
    half2_t* WhH  = (half2_t*)(G + (size_t)T * B * G4);
    half2_t* WaH  = WhH + (size_t)128 * G4;

    pack_whH<<<128, G4, 0, stream>>>(Whh, WhH);
    pack_waH<<<256, H, 0, stream>>>(Wa, WaH);
    dim3 ggrid(T * B / 64, G4 / 64);
    gemm_g<<<ggrid, 256, 0, stream>>>(embs, Wih, bih, bhh, G);
    alstm4<<<B / NB, 1024, 0, stream>>>(lens, G, WhH, WaH, ba, out);
}